// Round 3
// baseline (151.787 us; speedup 1.0000x reference)
//
#include <hip/hip_runtime.h>

// Problem constants (fixed by the reference)
#define BATCH   32
#define C_OUT_N 128
#define NK      5
#define C_IN_N  (NK * C_OUT_N)   // 640
#define HIN     58
#define WIN     58
#define HOUT    56
#define WOUT    56
#define NPIX    (HOUT * WOUT)                       // 3136
#define NQUAD   (HOUT * (WOUT / 4))                 // 784 quads of 4 pixels
#define OUT_PLANE ((size_t)BATCH * C_OUT_N * NPIX)  // 12,845,056

// Shift set is fixed: REAL_PAD[t] = 4 - 3*t for t in 0..4  ->  {4,1,-2,-5,-8}
// LDS tile: [NK][HIN][LDS_STRIDE] f32; cols padded 7 left / 3 right (zeroed).
// lds col for (pixel w, shift s) = w + 8 + s; quad w0: cols w0 .. w0+15.
// LDS_STRIDE*4 = 272 B (multiple of 16) -> float4 loads at w0%4==0 are aligned.
#define LDS_STRIDE 68
#define LDS_ROWS   (NK * HIN)                // 290
#define LDS_DWORDS (LDS_ROWS * LDS_STRIDE)   // 19720 (78,880 B -> 2 blocks/CU)
#define CH_STRIDE  (HIN * LDS_STRIDE)        // 3944

__global__ __launch_bounds__(256, 2) void addshift_quad_kernel(
    const float* __restrict__ x,          // (B, C_IN, 58, 58)
    const int*   __restrict__ pad_hv,     // (C_IN, 8): [0..3]=h shifts, [4..7]=v shifts
    const int*   __restrict__ idx_id,     // (C_OUT, 4), values in [co*5, co*5+5)
    float*       __restrict__ out)        // out_h | out_v | out_id concatenated
{
    extern __shared__ float lds[];

    const int bc  = blockIdx.x;           // b * C_OUT + co
    const int b   = bc / C_OUT_N;
    const int co  = bc - b * C_OUT_N;
    const int tid = threadIdx.x;

    // ---- zero the column margins (disjoint from interior; no barrier needed yet)
    for (int i = tid; i < LDS_ROWS * 10; i += 256) {
        int j = i / 10;
        int m = i - j * 10;
        int c = (m < 7) ? m : (58 + m);    // left pad 0..6, right pad 65..67
        lds[j * LDS_STRIDE + c] = 0.0f;
    }

    // ---- stage the contiguous 5-channel chunk into padded LDS (read x once)
    const float* xbase = x + (size_t)(b * C_IN_N + co * NK) * (HIN * WIN);
    for (int i = tid; i < NK * HIN * WIN; i += 256) {
        int j = i / WIN;
        int c = i - j * WIN;
        lds[j * LDS_STRIDE + 7 + c] = xbase[i];
    }

    // ---- shift multiplicities as float weights (block-uniform; static indexing)
    float mhf[NK][5], mvf[NK][5], cntf[NK];
    #pragma unroll
    for (int k = 0; k < NK; ++k) {
        #pragma unroll
        for (int t = 0; t < 5; ++t) { mhf[k][t] = 0.f; mvf[k][t] = 0.f; }
        cntf[k] = 0.f;
        #pragma unroll
        for (int g = 0; g < 4; ++g) {
            int sh_v = pad_hv[(co * NK + k) * 8 + g];       // in {4,1,-2,-5,-8}
            int th   = (4 - sh_v) / 3;                      // slot 0..4
            int sv_v = pad_hv[(co * NK + k) * 8 + 4 + g];
            int tv   = (4 - sv_v) / 3;
            #pragma unroll
            for (int t = 0; t < 5; ++t) {
                mhf[k][t] += (th == t) ? 1.f : 0.f;
                mvf[k][t] += (tv == t) ? 1.f : 0.f;
            }
        }
    }
    #pragma unroll
    for (int g = 0; g < 4; ++g) {
        int c = idx_id[co * 4 + g] - co * NK;               // 0..4
        #pragma unroll
        for (int k = 0; k < NK; ++k) cntf[k] += (c == k) ? 1.f : 0.f;
    }

    __syncthreads();

    // ---- compute: each thread owns a 4-pixel quad; all reads are ds_read_b128
    for (int q = tid; q < NQUAD; q += 256) {
        int h  = q / (WOUT / 4);
        int qq = q - h * (WOUT / 4);
        int w0 = qq * 4;

        float sh0 = 0.f, sh1 = 0.f, sh2 = 0.f, sh3 = 0.f;
        float sv0 = 0.f, sv1 = 0.f, sv2 = 0.f, sv3 = 0.f;
        float si0 = 0.f, si1 = 0.f, si2 = 0.f, si3 = 0.f;

        #pragma unroll
        for (int k = 0; k < NK; ++k) {
            const float* ch   = lds + k * CH_STRIDE;
            const float* rowp = ch + (h + 1) * LDS_STRIDE + w0;

            float4 A = *(const float4*)(rowp);
            float4 Bv = *(const float4*)(rowp + 4);
            float4 Cv = *(const float4*)(rowp + 8);
            float4 Dv = *(const float4*)(rowp + 12);
            float rr[16] = { A.x, A.y, A.z, A.w,  Bv.x, Bv.y, Bv.z, Bv.w,
                             Cv.x, Cv.y, Cv.z, Cv.w, Dv.x, Dv.y, Dv.z, Dv.w };

            // out_h: sh[i] += mhf[k][t] * rr[i + 12 - 3t]
            #pragma unroll
            for (int t = 0; t < 5; ++t) {
                float wgt = mhf[k][t];
                int j = 12 - 3 * t;
                sh0 += wgt * rr[j + 0];
                sh1 += wgt * rr[j + 1];
                sh2 += wgt * rr[j + 2];
                sh3 += wgt * rr[j + 3];
            }

            // out_id: center col = i + 8 (reuses the same row registers)
            si0 += cntf[k] * rr[8];
            si1 += cntf[k] * rr[9];
            si2 += cntf[k] * rr[10];
            si3 += cntf[k] * rr[11];

            // out_v: one aligned float4 per shift row
            #pragma unroll
            for (int t = 0; t < 5; ++t) {
                int rrow = h + 1 + (4 - 3 * t);
                int rc   = rrow < 0 ? 0 : (rrow > 57 ? 57 : rrow);
                float4 V = *(const float4*)(ch + rc * LDS_STRIDE + w0 + 8);
                float wv = ((unsigned)rrow < 58u) ? mvf[k][t] : 0.f;
                sv0 += wv * V.x;
                sv1 += wv * V.y;
                sv2 += wv * V.z;
                sv3 += wv * V.w;
            }
        }

        size_t o = (size_t)bc * NPIX + h * WOUT + w0;
        *(float4*)(out + o)                 = make_float4(sh0, sh1, sh2, sh3);
        *(float4*)(out + OUT_PLANE + o)     = make_float4(sv0, sv1, sv2, sv3);
        *(float4*)(out + 2 * OUT_PLANE + o) = make_float4(si0, si1, si2, si3);
    }
}

extern "C" void kernel_launch(void* const* d_in, const int* in_sizes, int n_in,
                              void* d_out, int out_size, void* d_ws, size_t ws_size,
                              hipStream_t stream) {
    const float* x      = (const float*)d_in[0];
    const int*   pad_hv = (const int*)d_in[1];
    const int*   idx_id = (const int*)d_in[2];
    float*       out    = (float*)d_out;

    addshift_quad_kernel<<<dim3(BATCH * C_OUT_N), dim3(256), LDS_DWORDS * 4, stream>>>(
        x, pad_hv, idx_id, out);
}